// Round 1
// baseline (981.837 us; speedup 1.0000x reference)
//
#include <hip/hip_runtime.h>
#include <stdint.h>

// Experts MLP: out[b,e] = gelu_exact(x[b,e] @ w1[e] + b1[e]) @ w2[e] + b2[e]
// B=4 E=8 N=1024 D=1024 H=4096. Strategy: convert/transpose operands to bf16
// in ws, then two m97-style 128x128-tile MFMA GEMMs (16x16x32 bf16).

typedef __attribute__((ext_vector_type(8))) short short8;
typedef __attribute__((ext_vector_type(4))) float f32x4;

__device__ __forceinline__ unsigned short f2b(float f){
  union { float f; unsigned int u; } v; v.f = f;
  unsigned int r = v.u + 0x7fffu + ((v.u >> 16) & 1u);   // RNE
  return (unsigned short)(r >> 16);
}

__device__ __forceinline__ void glds16(const void* g, const void* l){
  // async global->LDS, 16B per lane; LDS dest = wave-uniform base + lane*16
  __builtin_amdgcn_global_load_lds((const __attribute__((address_space(1))) uint32_t*)g,
                                   (__attribute__((address_space(3))) uint32_t*)l, 16, 0, 0);
}

// ---------------- prep kernels ----------------

__global__ void cvt_x_kernel(const float* __restrict__ src, unsigned short* __restrict__ dst, int n4){
  int i = blockIdx.x * blockDim.x + threadIdx.x;
  int stride = gridDim.x * blockDim.x;
  for (; i < n4; i += stride){
    float4 v = ((const float4*)src)[i];
    ushort4 o;
    o.x = f2b(v.x); o.y = f2b(v.y); o.z = f2b(v.z); o.w = f2b(v.w);
    ((ushort4*)dst)[i] = o;
  }
}

// src: per-e [R][C] f32 ; dst: per-e [C][R] bf16  (transpose + convert)
__global__ void transpose_cvt(const float* __restrict__ src, unsigned short* __restrict__ dst, int R, int C){
  __shared__ float t[64][65];
  const int e = blockIdx.z;
  src += (size_t)e * R * C;
  dst += (size_t)e * R * C;
  const int r0 = blockIdx.y * 64, c0 = blockIdx.x * 64;
  const int tid = threadIdx.x;
  const int lr = tid >> 4;           // 0..15
  const int lc4 = (tid & 15) * 4;    // 0..60
  #pragma unroll
  for (int p2 = 0; p2 < 4; p2++){
    int r = lr + p2 * 16;
    float4 v = *(const float4*)(src + (size_t)(r0 + r) * C + (c0 + lc4));
    t[r][lc4+0] = v.x; t[r][lc4+1] = v.y; t[r][lc4+2] = v.z; t[r][lc4+3] = v.w;
  }
  __syncthreads();
  #pragma unroll
  for (int p2 = 0; p2 < 4; p2++){
    int c = lr + p2 * 16;
    ushort4 o;
    o.x = f2b(t[lc4+0][c]); o.y = f2b(t[lc4+1][c]);
    o.z = f2b(t[lc4+2][c]); o.w = f2b(t[lc4+3][c]);
    *(ushort4*)(dst + (size_t)(c0 + c) * R + (r0 + lc4)) = o;
  }
}

// ---------------- GEMM (m97 structure) ----------------
// A: [M][K] bf16 (K contiguous). Bt: per-expert [Nd][K] bf16 (K contiguous).
// PHASE1: out = bf16 gelu(A@Bt^T + bias) -> h ws (chunk-local pair index)
// PHASE2: out = f32  A@Bt^T + bias       -> d_out (global pair index)
template<int PHASE1>
__global__ __launch_bounds__(256, 2) void gemm_bt(
    const unsigned short* __restrict__ A,
    const unsigned short* __restrict__ Bt,
    const float* __restrict__ bias,
    void* __restrict__ Out,
    int p0)
{
  constexpr int M  = 1024;
  constexpr int K  = PHASE1 ? 1024 : 4096;
  constexpr int Nd = PHASE1 ? 4096 : 1024;
  constexpr int nTN = Nd / 128;

  const int cp = blockIdx.y;        // chunk-local pair
  const int p  = p0 + cp;           // global pair
  const int e  = p & 7;             // E=8
  const int tm = blockIdx.x / nTN, tn = blockIdx.x % nTN;
  const int m0 = tm * 128, n0 = tn * 128;

  const unsigned short* Ap = A  + (size_t)(PHASE1 ? p : cp) * M * K;
  const unsigned short* Bp = Bt + (size_t)e * Nd * K;
  const float*          bp = bias + (size_t)e * Nd;

  __shared__ __align__(16) unsigned short As[128 * 32];
  __shared__ __align__(16) unsigned short Bs[128 * 32];

  const int tid = threadIdx.x;
  const int w = tid >> 6, lane = tid & 63;
  const int wr = w >> 1, wc = w & 1;          // wave tile 64x64 in 2x2
  const int sr = lane >> 2, sc = lane & 3;    // staging: 16 rows x 4 chunks per issue
  const int c15 = lane & 15, q = lane >> 4;   // frag: row/col + k-chunk

  f32x4 acc[4][4];
  #pragma unroll
  for (int i = 0; i < 4; i++)
    #pragma unroll
    for (int j = 0; j < 4; j++) acc[i][j] = (f32x4)0.f;

  for (int kt = 0; kt < K / 32; ++kt){
    const int k0 = kt * 32;
    // stage A-tile [128][32] and Bt-tile [128][32] (bf16), swizzled source:
    // LDS slot (row, c) holds global chunk c ^ ((row>>1)&3)  (16B chunks)
    #pragma unroll
    for (int i = 0; i < 2; i++){
      const int rl = w * 32 + i * 16 + sr;
      const int gc = sc ^ ((rl >> 1) & 3);
      glds16(Ap + (size_t)(m0 + rl) * K + k0 + gc * 8, &As[(w * 32 + i * 16) * 32]);
      glds16(Bp + (size_t)(n0 + rl) * K + k0 + gc * 8, &Bs[(w * 32 + i * 16) * 32]);
    }
    __syncthreads();   // drains vmcnt -> tiles ready

    short8 af[4], bf[4];
    #pragma unroll
    for (int i = 0; i < 4; i++){
      int ra = wr * 64 + i * 16 + c15;
      af[i] = *(const short8*)&As[ra * 32 + ((q ^ ((ra >> 1) & 3)) << 3)];
      int rb = wc * 64 + i * 16 + c15;
      bf[i] = *(const short8*)&Bs[rb * 32 + ((q ^ ((rb >> 1) & 3)) << 3)];
    }
    #pragma unroll
    for (int i = 0; i < 4; i++)
      #pragma unroll
      for (int j = 0; j < 4; j++)
        acc[i][j] = __builtin_amdgcn_mfma_f32_16x16x32_bf16(af[i], bf[j], acc[i][j], 0, 0, 0);
    __syncthreads();   // all waves done reading before restage
  }

  // epilogue: C/D layout col = lane&15, row = (lane>>4)*4 + r  (m89-verified)
  #pragma unroll
  for (int j = 0; j < 4; j++){
    const int col = n0 + wc * 64 + j * 16 + c15;
    const float bv = bp[col];
    #pragma unroll
    for (int i = 0; i < 4; i++){
      const int rbase = m0 + wr * 64 + i * 16 + q * 4;
      #pragma unroll
      for (int r = 0; r < 4; r++){
        float v = acc[i][j][r] + bv;
        if constexpr (PHASE1){
          v = 0.5f * v * (1.0f + erff(v * 0.70710678118654752f));  // exact GELU
          ((unsigned short*)Out)[(size_t)cp * M * Nd + (size_t)(rbase + r) * Nd + col] = f2b(v);
        } else {
          ((float*)Out)[(size_t)p * M * Nd + (size_t)(rbase + r) * Nd + col] = v;
        }
      }
    }
  }
}

// ---------------- launch ----------------

extern "C" void kernel_launch(void* const* d_in, const int* in_sizes, int n_in,
                              void* d_out, int out_size, void* d_ws, size_t ws_size,
                              hipStream_t stream){
  const float* x  = (const float*)d_in[0];
  const float* w1 = (const float*)d_in[1];
  const float* b1 = (const float*)d_in[2];
  const float* w2 = (const float*)d_in[3];
  const float* b2 = (const float*)d_in[4];
  float* out = (float*)d_out;

  // ws layout: xb 64MB | w1t 64MB | w2t 64MB | h (bf16, 8MB/pair, chunked)
  unsigned short* xb  = (unsigned short*)d_ws;
  unsigned short* w1t = (unsigned short*)((char*)d_ws + ((size_t)64  << 20));
  unsigned short* w2t = (unsigned short*)((char*)d_ws + ((size_t)128 << 20));
  unsigned short* hb  = (unsigned short*)((char*)d_ws + ((size_t)192 << 20));

  size_t avail = ws_size > ((size_t)192 << 20) ? ws_size - ((size_t)192 << 20) : 0;
  int ppc = (int)(avail / ((size_t)8 << 20));   // pairs per h-chunk
  if (ppc > 32) ppc = 32;
  if (ppc < 1) return;   // ws too small for this design — visible failure

  cvt_x_kernel<<<2048, 256, 0, stream>>>(x, xb, 8 * 1024 * 1024);
  // w1[e]: [D=1024][H=4096] -> w1t[e]: [H][D]
  transpose_cvt<<<dim3(64, 16, 8), 256, 0, stream>>>(w1, w1t, 1024, 4096);
  // w2[e]: [H=4096][D=1024] -> w2t[e]: [D][H]
  transpose_cvt<<<dim3(16, 64, 8), 256, 0, stream>>>(w2, w2t, 4096, 1024);

  for (int p0 = 0; p0 < 32; p0 += ppc){
    int np = (32 - p0 < ppc) ? (32 - p0) : ppc;
    // GEMM1: h = gelu(xb @ w1t^T + b1)   [M=1024, K=1024, Nd=4096]
    gemm_bt<1><<<dim3(256, np), 256, 0, stream>>>(xb, w1t, b1, hb, p0);
    // GEMM2: out = h @ w2t^T + b2        [M=1024, K=4096, Nd=1024]
    gemm_bt<0><<<dim3(64, np), 256, 0, stream>>>(hb, w2t, b2, out, p0);
  }
}

// Round 2
// 712.707 us; speedup vs baseline: 1.3776x; 1.3776x over previous
//
#include <hip/hip_runtime.h>
#include <stdint.h>

// Experts MLP: out[b,e] = gelu_exact(x[b,e] @ w1[e] + b1[e]) @ w2[e] + b2[e]
// B=4 E=8 N=1024 D=1024 H=4096.
// Round 2: 256x256-tile 8-phase bf16 MFMA GEMM (T2 swizzle + T3/T4 counted
// vmcnt + T5 setprio), per the m201 template. Prep kernels unchanged.

typedef __attribute__((ext_vector_type(8))) short short8;
typedef __attribute__((ext_vector_type(4))) float f32x4;

__device__ __forceinline__ unsigned short f2b(float f){
  union { float f; unsigned int u; } v; v.f = f;
  unsigned int r = v.u + 0x7fffu + ((v.u >> 16) & 1u);   // RNE
  return (unsigned short)(r >> 16);
}

__device__ __forceinline__ void glds16(const void* g, const void* l){
  __builtin_amdgcn_global_load_lds((const __attribute__((address_space(1))) uint32_t*)g,
                                   (__attribute__((address_space(3))) uint32_t*)l, 16, 0, 0);
}

#define BAR() do{ asm volatile("" ::: "memory"); __builtin_amdgcn_s_barrier(); asm volatile("" ::: "memory"); }while(0)

// ---------------- prep kernels (verified round 1) ----------------

__global__ void cvt_x_kernel(const float* __restrict__ src, unsigned short* __restrict__ dst, int n4){
  int i = blockIdx.x * blockDim.x + threadIdx.x;
  int stride = gridDim.x * blockDim.x;
  for (; i < n4; i += stride){
    float4 v = ((const float4*)src)[i];
    ushort4 o;
    o.x = f2b(v.x); o.y = f2b(v.y); o.z = f2b(v.z); o.w = f2b(v.w);
    ((ushort4*)dst)[i] = o;
  }
}

__global__ void transpose_cvt(const float* __restrict__ src, unsigned short* __restrict__ dst, int R, int C){
  __shared__ float t[64][65];
  const int e = blockIdx.z;
  src += (size_t)e * R * C;
  dst += (size_t)e * R * C;
  const int r0 = blockIdx.y * 64, c0 = blockIdx.x * 64;
  const int tid = threadIdx.x;
  const int lr = tid >> 4;
  const int lc4 = (tid & 15) * 4;
  #pragma unroll
  for (int p2 = 0; p2 < 4; p2++){
    int r = lr + p2 * 16;
    float4 v = *(const float4*)(src + (size_t)(r0 + r) * C + (c0 + lc4));
    t[r][lc4+0] = v.x; t[r][lc4+1] = v.y; t[r][lc4+2] = v.z; t[r][lc4+3] = v.w;
  }
  __syncthreads();
  #pragma unroll
  for (int p2 = 0; p2 < 4; p2++){
    int c = lr + p2 * 16;
    ushort4 o;
    o.x = f2b(t[lc4+0][c]); o.y = f2b(t[lc4+1][c]);
    o.z = f2b(t[lc4+2][c]); o.w = f2b(t[lc4+3][c]);
    *(ushort4*)(dst + (size_t)(c0 + c) * R + (r0 + lc4)) = o;
  }
}

// ---------------- 256x256 8-phase GEMM ----------------
// LDS tile rows are 64 bf16 (128B = 8 x 16B chunks). Chunk c of row r lives at
// LDS chunk (c ^ (r&7)) -> conflict-free ds_read_b128 (verified 0 conflicts r1).
// LDS itself stays LINEAR in staging order; the global SOURCE is pre-swizzled
// per-lane (guide rule #21).

__device__ __forceinline__ short8 ldfrag(const unsigned short* l, int row, int kk, int q){
  int c = ((kk << 2) + q) ^ (row & 7);
  return *(const short8*)(l + row * 64 + (c << 3));
}

// stage 64 rows [R0, R0+64) of a [256 x 64] bf16 tile; 1 issue/thread (16B)
__device__ __forceinline__ void stage64(const unsigned short* g, size_t ld,
                                        unsigned short* l, int R0, int w, int lane){
  int r = R0 + (w << 3) + (lane >> 3);
  int c = (lane & 7) ^ (r & 7);
  glds16(g + (size_t)r * ld + (c << 3), l + ((R0 + (w << 3)) << 6));
}

template<int PHASE1>
__global__ __launch_bounds__(512, 2) void gemm256(
    const unsigned short* __restrict__ A,
    const unsigned short* __restrict__ Bt,
    const float* __restrict__ bias,
    void* __restrict__ Out,
    int p0)
{
  constexpr int M  = 1024;
  constexpr int K  = PHASE1 ? 1024 : 4096;
  constexpr int Nd = PHASE1 ? 4096 : 1024;
  constexpr int TM = M / 256, TN = Nd / 256;
  constexpr int NT = K / 64;

  // XCD-bijective swizzle (nwg % 8 == 0 by construction)
  const int cpx = gridDim.x >> 3;
  const int bid = (blockIdx.x & 7) * cpx + (blockIdx.x >> 3);
  const int tn = bid % TN;
  const int t2 = bid / TN;
  const int tm = t2 % TM;
  const int cp = t2 / TM;
  const int p  = p0 + cp, e = p & 7;
  const int m0 = tm * 256, n0 = tn * 256;

  const unsigned short* Ag = A  + (size_t)(PHASE1 ? p : cp) * M * K + (size_t)m0 * K;
  const unsigned short* Bg = Bt + (size_t)e * Nd * K + (size_t)n0 * K;
  const float*          bp = bias + (size_t)e * Nd;

  // 128 KiB: A0 | A1 | B0 | B1, each 256x64 bf16 = 32 KiB
  __shared__ __align__(16) unsigned short lds[65536];

  const int tid = threadIdx.x;
  const int w = tid >> 6, lane = tid & 63;
  const int wr = w >> 2, wc = w & 3;          // 2 x 4 waves; wave tile 128 x 64
  const int c15 = lane & 15, q = lane >> 4;

  f32x4 acc[8][4];
  #pragma unroll
  for (int i = 0; i < 8; i++)
    #pragma unroll
    for (int j = 0; j < 4; j++) acc[i][j] = (f32x4)0.f;

  // ---- prologue: stage tile 0 (A 4 issues + B 4 issues) + h0(tile 1) ----
  stage64(Ag, K, lds,          0, w, lane);
  stage64(Ag, K, lds,         64, w, lane);
  stage64(Ag, K, lds,        128, w, lane);
  stage64(Ag, K, lds,        192, w, lane);
  stage64(Bg, K, lds + 32768,  0, w, lane);
  stage64(Bg, K, lds + 32768, 64, w, lane);
  stage64(Bg, K, lds + 32768,128, w, lane);
  stage64(Bg, K, lds + 32768,192, w, lane);
  if (NT > 1){
    stage64(Ag + 64, K, lds + 16384,  0, w, lane);
    stage64(Ag + 64, K, lds + 16384, 64, w, lane);
    asm volatile("s_waitcnt vmcnt(2)" ::: "memory");
  } else {
    asm volatile("s_waitcnt vmcnt(0)" ::: "memory");
  }
  BAR();

  short8 af[4][2], bf0[2][2], bf1[2][2];

  for (int kt = 0; kt < NT; ++kt){
    const int cb = kt & 1;
    unsigned short* Al  = lds + (cb << 14);
    unsigned short* Aln = lds + ((cb ^ 1) << 14);
    unsigned short* Bl  = lds + 32768 + (cb << 14);
    unsigned short* Bln = lds + 32768 + ((cb ^ 1) << 14);
    const unsigned short* Agn  = Ag + (size_t)(kt + 1) * 64;
    const unsigned short* Agn2 = Ag + (size_t)(kt + 2) * 64;
    const unsigned short* Bgn  = Bg + (size_t)(kt + 1) * 64;
    const bool pf1 = (kt + 1 < NT), pf2 = (kt + 2 < NT);

    // ---- phase 0: quadrant (m0, n0). stage h1(kt+1)=A rows 128..255 ----
    if (pf1){ stage64(Agn, K, Aln, 128, w, lane); stage64(Agn, K, Aln, 192, w, lane); }
    {
      const int ra = wr * 128 + c15, rb = wc * 64 + c15;
      #pragma unroll
      for (int mf = 0; mf < 4; ++mf)
        #pragma unroll
        for (int kk = 0; kk < 2; ++kk) af[mf][kk] = ldfrag(Al, ra + mf * 16, kk, q);
      #pragma unroll
      for (int nf = 0; nf < 2; ++nf)
        #pragma unroll
        for (int kk = 0; kk < 2; ++kk) bf0[nf][kk] = ldfrag(Bl, rb + nf * 16, kk, q);
    }
    BAR();
    __builtin_amdgcn_s_setprio(1);
    #pragma unroll
    for (int mf = 0; mf < 4; ++mf)
      #pragma unroll
      for (int nf = 0; nf < 2; ++nf)
        #pragma unroll
        for (int kk = 0; kk < 2; ++kk)
          acc[mf][nf] = __builtin_amdgcn_mfma_f32_16x16x32_bf16(af[mf][kk], bf0[nf][kk], acc[mf][nf], 0, 0, 0);
    __builtin_amdgcn_s_setprio(0);
    BAR();

    // ---- phase 1: quadrant (m0, n1). stage h2(kt+1)=B rows 0..127 ----
    if (pf1){ stage64(Bgn, K, Bln, 0, w, lane); stage64(Bgn, K, Bln, 64, w, lane); }
    {
      const int rb = wc * 64 + 32 + c15;
      #pragma unroll
      for (int nf = 0; nf < 2; ++nf)
        #pragma unroll
        for (int kk = 0; kk < 2; ++kk) bf1[nf][kk] = ldfrag(Bl, rb + nf * 16, kk, q);
    }
    BAR();
    __builtin_amdgcn_s_setprio(1);
    #pragma unroll
    for (int mf = 0; mf < 4; ++mf)
      #pragma unroll
      for (int nf = 0; nf < 2; ++nf)
        #pragma unroll
        for (int kk = 0; kk < 2; ++kk)
          acc[mf][2 + nf] = __builtin_amdgcn_mfma_f32_16x16x32_bf16(af[mf][kk], bf1[nf][kk], acc[mf][2 + nf], 0, 0, 0);
    __builtin_amdgcn_s_setprio(0);
    BAR();

    // ---- phase 2: quadrant (m1, n1). stage h3(kt+1)=B rows 128..255 ----
    if (pf1){ stage64(Bgn, K, Bln, 128, w, lane); stage64(Bgn, K, Bln, 192, w, lane); }
    {
      const int ra = wr * 128 + 64 + c15;
      #pragma unroll
      for (int mf = 0; mf < 4; ++mf)
        #pragma unroll
        for (int kk = 0; kk < 2; ++kk) af[mf][kk] = ldfrag(Al, ra + mf * 16, kk, q);
    }
    BAR();
    __builtin_amdgcn_s_setprio(1);
    #pragma unroll
    for (int mf = 0; mf < 4; ++mf)
      #pragma unroll
      for (int nf = 0; nf < 2; ++nf)
        #pragma unroll
        for (int kk = 0; kk < 2; ++kk)
          acc[4 + mf][2 + nf] = __builtin_amdgcn_mfma_f32_16x16x32_bf16(af[mf][kk], bf1[nf][kk], acc[4 + mf][2 + nf], 0, 0, 0);
    __builtin_amdgcn_s_setprio(0);
    BAR();

    // ---- phase 3: quadrant (m1, n0), register-only. stage h0(kt+2) into
    //      the CURRENT A buffer (its last ds_read was phase 2). ----
    if (pf2){ stage64(Agn2, K, Al, 0, w, lane); stage64(Agn2, K, Al, 64, w, lane); }
    BAR();
    __builtin_amdgcn_s_setprio(1);
    #pragma unroll
    for (int mf = 0; mf < 4; ++mf)
      #pragma unroll
      for (int nf = 0; nf < 2; ++nf)
        #pragma unroll
        for (int kk = 0; kk < 2; ++kk)
          acc[4 + mf][nf] = __builtin_amdgcn_mfma_f32_16x16x32_bf16(af[mf][kk], bf0[nf][kk], acc[4 + mf][nf], 0, 0, 0);
    __builtin_amdgcn_s_setprio(0);
    // counted tile-boundary wait: tile kt+1 must be resident; h0(kt+2) (the
    // 2 newest issues) may stay in flight.
    if (pf1){
      if (pf2) asm volatile("s_waitcnt vmcnt(2)" ::: "memory");
      else     asm volatile("s_waitcnt vmcnt(0)" ::: "memory");
    }
    BAR();
  }

  // ---- epilogue: C/D layout col = lane&15, row = (lane>>4)*4 + r ----
  float bv[4];
  #pragma unroll
  for (int nf = 0; nf < 4; ++nf) bv[nf] = bp[n0 + wc * 64 + nf * 16 + c15];
  #pragma unroll
  for (int mf = 0; mf < 8; ++mf){
    const int row = m0 + wr * 128 + mf * 16 + q * 4;
    #pragma unroll
    for (int nf = 0; nf < 4; ++nf){
      const int col = n0 + wc * 64 + nf * 16 + c15;
      #pragma unroll
      for (int r = 0; r < 4; ++r){
        float v = acc[mf][nf][r] + bv[nf];
        if constexpr (PHASE1){
          v = 0.5f * v * (1.0f + erff(v * 0.70710678118654752f));
          ((unsigned short*)Out)[(size_t)cp * M * Nd + (size_t)(row + r) * Nd + col] = f2b(v);
        } else {
          ((float*)Out)[(size_t)p * M * Nd + (size_t)(row + r) * Nd + col] = v;
        }
      }
    }
  }
}

// ---------------- launch ----------------

extern "C" void kernel_launch(void* const* d_in, const int* in_sizes, int n_in,
                              void* d_out, int out_size, void* d_ws, size_t ws_size,
                              hipStream_t stream){
  const float* x  = (const float*)d_in[0];
  const float* w1 = (const float*)d_in[1];
  const float* b1 = (const float*)d_in[2];
  const float* w2 = (const float*)d_in[3];
  const float* b2 = (const float*)d_in[4];
  float* out = (float*)d_out;

  unsigned short* xb  = (unsigned short*)d_ws;
  unsigned short* w1t = (unsigned short*)((char*)d_ws + ((size_t)64  << 20));
  unsigned short* w2t = (unsigned short*)((char*)d_ws + ((size_t)128 << 20));
  unsigned short* hb  = (unsigned short*)((char*)d_ws + ((size_t)192 << 20));

  size_t avail = ws_size > ((size_t)192 << 20) ? ws_size - ((size_t)192 << 20) : 0;
  int ppc = (int)(avail / ((size_t)8 << 20));
  if (ppc > 32) ppc = 32;
  if (ppc < 1) return;

  cvt_x_kernel<<<2048, 256, 0, stream>>>(x, xb, 8 * 1024 * 1024);
  transpose_cvt<<<dim3(64, 16, 8), 256, 0, stream>>>(w1, w1t, 1024, 4096);
  transpose_cvt<<<dim3(16, 64, 8), 256, 0, stream>>>(w2, w2t, 4096, 1024);

  for (int p0 = 0; p0 < 32; p0 += ppc){
    int np = (32 - p0 < ppc) ? (32 - p0) : ppc;
    // GEMM1: h = gelu(xb @ w1t^T + b1)   [M=1024, K=1024, Nd=4096]
    gemm256<1><<<dim3(np * 4 * 16), 512, 0, stream>>>(xb, w1t, b1, hb, p0);
    // GEMM2: out = h @ w2t^T + b2        [M=1024, K=4096, Nd=1024]
    gemm256<0><<<dim3(np * 4 * 4),  512, 0, stream>>>(hb, w2t, b2, out, p0);
  }
}

// Round 3
// 639.498 us; speedup vs baseline: 1.5353x; 1.1145x over previous
//
#include <hip/hip_runtime.h>
#include <stdint.h>

// Experts MLP: out[b,e] = gelu_exact(x[b,e] @ w1[e] + b1[e]) @ w2[e] + b2[e]
// B=4 E=8 N=1024 D=1024 H=4096.
// Round 3: keep the 256x256 8-phase bf16 MFMA GEMM (passed r2, 0 bank
// conflicts). Fix the VALU-bound GELU epilogue (erff ~60 ops -> tanh-form
// GELU ~7 ops via v_exp/v_rcp), fold bias into acc init, ds-reads before
// stage issues per phase.

typedef __attribute__((ext_vector_type(8))) short short8;
typedef __attribute__((ext_vector_type(4))) float f32x4;

__device__ __forceinline__ unsigned short f2b(float f){
  union { float f; unsigned int u; } v; v.f = f;
  unsigned int r = v.u + 0x7fffu + ((v.u >> 16) & 1u);   // RNE
  return (unsigned short)(r >> 16);
}

// tanh-form GELU: v * sigma(1.5957691(v + 0.044715 v^3)); |err vs erf-GELU| <= ~5e-4
__device__ __forceinline__ float gelu_fast(float v){
  float v2 = v * v;
  // w = -log2(e) * 1.5957691216 * (v + 0.044715 v^3)
  float w = v * (-2.302217529693f + -0.102943795894f * v2);
  float e = __builtin_amdgcn_exp2f(w);          // e = 2^w = exp(-z)
  return v * __builtin_amdgcn_rcpf(1.0f + e);   // v * sigma(z)
}

__device__ __forceinline__ void glds16(const void* g, const void* l){
  __builtin_amdgcn_global_load_lds((const __attribute__((address_space(1))) uint32_t*)g,
                                   (__attribute__((address_space(3))) uint32_t*)l, 16, 0, 0);
}

#define BAR() do{ asm volatile("" ::: "memory"); __builtin_amdgcn_s_barrier(); asm volatile("" ::: "memory"); }while(0)

// ---------------- prep kernels (verified r1/r2) ----------------

__global__ void cvt_x_kernel(const float* __restrict__ src, unsigned short* __restrict__ dst, int n4){
  int i = blockIdx.x * blockDim.x + threadIdx.x;
  int stride = gridDim.x * blockDim.x;
  for (; i < n4; i += stride){
    float4 v = ((const float4*)src)[i];
    ushort4 o;
    o.x = f2b(v.x); o.y = f2b(v.y); o.z = f2b(v.z); o.w = f2b(v.w);
    ((ushort4*)dst)[i] = o;
  }
}

__global__ void transpose_cvt(const float* __restrict__ src, unsigned short* __restrict__ dst, int R, int C){
  __shared__ float t[64][65];
  const int e = blockIdx.z;
  src += (size_t)e * R * C;
  dst += (size_t)e * R * C;
  const int r0 = blockIdx.y * 64, c0 = blockIdx.x * 64;
  const int tid = threadIdx.x;
  const int lr = tid >> 4;
  const int lc4 = (tid & 15) * 4;
  #pragma unroll
  for (int p2 = 0; p2 < 4; p2++){
    int r = lr + p2 * 16;
    float4 v = *(const float4*)(src + (size_t)(r0 + r) * C + (c0 + lc4));
    t[r][lc4+0] = v.x; t[r][lc4+1] = v.y; t[r][lc4+2] = v.z; t[r][lc4+3] = v.w;
  }
  __syncthreads();
  #pragma unroll
  for (int p2 = 0; p2 < 4; p2++){
    int c = lr + p2 * 16;
    ushort4 o;
    o.x = f2b(t[lc4+0][c]); o.y = f2b(t[lc4+1][c]);
    o.z = f2b(t[lc4+2][c]); o.w = f2b(t[lc4+3][c]);
    *(ushort4*)(dst + (size_t)(c0 + c) * R + (r0 + lc4)) = o;
  }
}

// ---------------- 256x256 8-phase GEMM ----------------
// LDS rows = 64 bf16 (8 x 16B chunks); chunk c of row r lives at LDS chunk
// (c ^ (r&7)): conflict-free ds_read_b128, LDS linear + pre-swizzled source.

__device__ __forceinline__ short8 ldfrag(const unsigned short* l, int row, int kk, int q){
  int c = ((kk << 2) + q) ^ (row & 7);
  return *(const short8*)(l + row * 64 + (c << 3));
}

__device__ __forceinline__ void stage64(const unsigned short* g, size_t ld,
                                        unsigned short* l, int R0, int w, int lane){
  int r = R0 + (w << 3) + (lane >> 3);
  int c = (lane & 7) ^ (r & 7);
  glds16(g + (size_t)r * ld + (c << 3), l + ((R0 + (w << 3)) << 6));
}

template<int PHASE1>
__global__ __launch_bounds__(512, 2) void gemm256(
    const unsigned short* __restrict__ A,
    const unsigned short* __restrict__ Bt,
    const float* __restrict__ bias,
    void* __restrict__ Out,
    int p0)
{
  constexpr int M  = 1024;
  constexpr int K  = PHASE1 ? 1024 : 4096;
  constexpr int Nd = PHASE1 ? 4096 : 1024;
  constexpr int TM = M / 256, TN = Nd / 256;
  constexpr int NT = K / 64;

  const int cpx = gridDim.x >> 3;
  const int bid = (blockIdx.x & 7) * cpx + (blockIdx.x >> 3);
  const int tn = bid % TN;
  const int t2 = bid / TN;
  const int tm = t2 % TM;
  const int cp = t2 / TM;
  const int p  = p0 + cp, e = p & 7;
  const int m0 = tm * 256, n0 = tn * 256;

  const unsigned short* Ag = A  + (size_t)(PHASE1 ? p : cp) * M * K + (size_t)m0 * K;
  const unsigned short* Bg = Bt + (size_t)e * Nd * K + (size_t)n0 * K;
  const float*          bp = bias + (size_t)e * Nd;

  __shared__ __align__(16) unsigned short lds[65536];

  const int tid = threadIdx.x;
  const int w = tid >> 6, lane = tid & 63;
  const int wr = w >> 2, wc = w & 3;          // 2 x 4 waves; wave tile 128 x 64
  const int c15 = lane & 15, q = lane >> 4;

  // bias folded into accumulator init (per-col value, shared by all 4 rows)
  float bv[4];
  #pragma unroll
  for (int nf = 0; nf < 4; ++nf) bv[nf] = bp[n0 + wc * 64 + nf * 16 + c15];

  f32x4 acc[8][4];
  #pragma unroll
  for (int i = 0; i < 8; i++)
    #pragma unroll
    for (int j = 0; j < 4; j++) acc[i][j] = (f32x4)(bv[j]);

  // ---- prologue: stage tile 0 + h0(tile 1) ----
  stage64(Ag, K, lds,          0, w, lane);
  stage64(Ag, K, lds,         64, w, lane);
  stage64(Ag, K, lds,        128, w, lane);
  stage64(Ag, K, lds,        192, w, lane);
  stage64(Bg, K, lds + 32768,  0, w, lane);
  stage64(Bg, K, lds + 32768, 64, w, lane);
  stage64(Bg, K, lds + 32768,128, w, lane);
  stage64(Bg, K, lds + 32768,192, w, lane);
  if (NT > 1){
    stage64(Ag + 64, K, lds + 16384,  0, w, lane);
    stage64(Ag + 64, K, lds + 16384, 64, w, lane);
    asm volatile("s_waitcnt vmcnt(2)" ::: "memory");
  } else {
    asm volatile("s_waitcnt vmcnt(0)" ::: "memory");
  }
  BAR();

  short8 af[4][2], bf0[2][2], bf1[2][2];

  for (int kt = 0; kt < NT; ++kt){
    const int cb = kt & 1;
    unsigned short* Al  = lds + (cb << 14);
    unsigned short* Aln = lds + ((cb ^ 1) << 14);
    unsigned short* Bl  = lds + 32768 + (cb << 14);
    unsigned short* Bln = lds + 32768 + ((cb ^ 1) << 14);
    const unsigned short* Agn  = Ag + (size_t)(kt + 1) * 64;
    const unsigned short* Agn2 = Ag + (size_t)(kt + 2) * 64;
    const unsigned short* Bgn  = Bg + (size_t)(kt + 1) * 64;
    const bool pf1 = (kt + 1 < NT), pf2 = (kt + 2 < NT);

    // ---- phase 0: quadrant (m0, n0); stage A(kt+1) rows 128..255 ----
    {
      const int ra = wr * 128 + c15, rb = wc * 64 + c15;
      #pragma unroll
      for (int mf = 0; mf < 4; ++mf)
        #pragma unroll
        for (int kk = 0; kk < 2; ++kk) af[mf][kk] = ldfrag(Al, ra + mf * 16, kk, q);
      #pragma unroll
      for (int nf = 0; nf < 2; ++nf)
        #pragma unroll
        for (int kk = 0; kk < 2; ++kk) bf0[nf][kk] = ldfrag(Bl, rb + nf * 16, kk, q);
    }
    if (pf1){ stage64(Agn, K, Aln, 128, w, lane); stage64(Agn, K, Aln, 192, w, lane); }
    BAR();
    __builtin_amdgcn_s_setprio(1);
    #pragma unroll
    for (int mf = 0; mf < 4; ++mf)
      #pragma unroll
      for (int nf = 0; nf < 2; ++nf)
        #pragma unroll
        for (int kk = 0; kk < 2; ++kk)
          acc[mf][nf] = __builtin_amdgcn_mfma_f32_16x16x32_bf16(af[mf][kk], bf0[nf][kk], acc[mf][nf], 0, 0, 0);
    __builtin_amdgcn_s_setprio(0);
    BAR();

    // ---- phase 1: quadrant (m0, n1); stage B(kt+1) rows 0..127 ----
    {
      const int rb = wc * 64 + 32 + c15;
      #pragma unroll
      for (int nf = 0; nf < 2; ++nf)
        #pragma unroll
        for (int kk = 0; kk < 2; ++kk) bf1[nf][kk] = ldfrag(Bl, rb + nf * 16, kk, q);
    }
    if (pf1){ stage64(Bgn, K, Bln, 0, w, lane); stage64(Bgn, K, Bln, 64, w, lane); }
    BAR();
    __builtin_amdgcn_s_setprio(1);
    #pragma unroll
    for (int mf = 0; mf < 4; ++mf)
      #pragma unroll
      for (int nf = 0; nf < 2; ++nf)
        #pragma unroll
        for (int kk = 0; kk < 2; ++kk)
          acc[mf][2 + nf] = __builtin_amdgcn_mfma_f32_16x16x32_bf16(af[mf][kk], bf1[nf][kk], acc[mf][2 + nf], 0, 0, 0);
    __builtin_amdgcn_s_setprio(0);
    BAR();

    // ---- phase 2: quadrant (m1, n1); stage B(kt+1) rows 128..255 ----
    {
      const int ra = wr * 128 + 64 + c15;
      #pragma unroll
      for (int mf = 0; mf < 4; ++mf)
        #pragma unroll
        for (int kk = 0; kk < 2; ++kk) af[mf][kk] = ldfrag(Al, ra + mf * 16, kk, q);
    }
    if (pf1){ stage64(Bgn, K, Bln, 128, w, lane); stage64(Bgn, K, Bln, 192, w, lane); }
    BAR();
    __builtin_amdgcn_s_setprio(1);
    #pragma unroll
    for (int mf = 0; mf < 4; ++mf)
      #pragma unroll
      for (int nf = 0; nf < 2; ++nf)
        #pragma unroll
        for (int kk = 0; kk < 2; ++kk)
          acc[4 + mf][2 + nf] = __builtin_amdgcn_mfma_f32_16x16x32_bf16(af[mf][kk], bf1[nf][kk], acc[4 + mf][2 + nf], 0, 0, 0);
    __builtin_amdgcn_s_setprio(0);
    BAR();

    // ---- phase 3: quadrant (m1, n0) register-only; stage A(kt+2) rows
    //      0..127 into CURRENT A buffer (safe: its reads ended phase 2) ----
    if (pf2){ stage64(Agn2, K, Al, 0, w, lane); stage64(Agn2, K, Al, 64, w, lane); }
    BAR();
    __builtin_amdgcn_s_setprio(1);
    #pragma unroll
    for (int mf = 0; mf < 4; ++mf)
      #pragma unroll
      for (int nf = 0; nf < 2; ++nf)
        #pragma unroll
        for (int kk = 0; kk < 2; ++kk)
          acc[4 + mf][nf] = __builtin_amdgcn_mfma_f32_16x16x32_bf16(af[mf][kk], bf0[nf][kk], acc[4 + mf][nf], 0, 0, 0);
    __builtin_amdgcn_s_setprio(0);
    // counted tile-boundary wait: tile kt+1 resident; A(kt+2)lo may fly on
    if (pf1){
      if (pf2) asm volatile("s_waitcnt vmcnt(2)" ::: "memory");
      else     asm volatile("s_waitcnt vmcnt(0)" ::: "memory");
    }
    BAR();
  }

  // ---- epilogue: C/D layout col = lane&15, row = (lane>>4)*4 + r ----
  #pragma unroll
  for (int mf = 0; mf < 8; ++mf){
    const int row = m0 + wr * 128 + mf * 16 + q * 4;
    #pragma unroll
    for (int nf = 0; nf < 4; ++nf){
      const int col = n0 + wc * 64 + nf * 16 + c15;
      #pragma unroll
      for (int r = 0; r < 4; ++r){
        float v = acc[mf][nf][r];          // bias already folded in
        if constexpr (PHASE1){
          ((unsigned short*)Out)[(size_t)cp * M * Nd + (size_t)(row + r) * Nd + col] = f2b(gelu_fast(v));
        } else {
          ((float*)Out)[(size_t)p * M * Nd + (size_t)(row + r) * Nd + col] = v;
        }
      }
    }
  }
}

// ---------------- launch ----------------

extern "C" void kernel_launch(void* const* d_in, const int* in_sizes, int n_in,
                              void* d_out, int out_size, void* d_ws, size_t ws_size,
                              hipStream_t stream){
  const float* x  = (const float*)d_in[0];
  const float* w1 = (const float*)d_in[1];
  const float* b1 = (const float*)d_in[2];
  const float* w2 = (const float*)d_in[3];
  const float* b2 = (const float*)d_in[4];
  float* out = (float*)d_out;

  unsigned short* xb  = (unsigned short*)d_ws;
  unsigned short* w1t = (unsigned short*)((char*)d_ws + ((size_t)64  << 20));
  unsigned short* w2t = (unsigned short*)((char*)d_ws + ((size_t)128 << 20));
  unsigned short* hb  = (unsigned short*)((char*)d_ws + ((size_t)192 << 20));

  size_t avail = ws_size > ((size_t)192 << 20) ? ws_size - ((size_t)192 << 20) : 0;
  int ppc = (int)(avail / ((size_t)8 << 20));
  if (ppc > 32) ppc = 32;
  if (ppc < 1) return;

  cvt_x_kernel<<<2048, 256, 0, stream>>>(x, xb, 8 * 1024 * 1024);
  transpose_cvt<<<dim3(64, 16, 8), 256, 0, stream>>>(w1, w1t, 1024, 4096);
  transpose_cvt<<<dim3(16, 64, 8), 256, 0, stream>>>(w2, w2t, 4096, 1024);

  for (int p0 = 0; p0 < 32; p0 += ppc){
    int np = (32 - p0 < ppc) ? (32 - p0) : ppc;
    // GEMM1: h = gelu(xb @ w1t^T + b1)   [M=1024, K=1024, Nd=4096]
    gemm256<1><<<dim3(np * 4 * 16), 512, 0, stream>>>(xb, w1t, b1, hb, p0);
    // GEMM2: out = h @ w2t^T + b2        [M=1024, K=4096, Nd=1024]
    gemm256<0><<<dim3(np * 4 * 4),  512, 0, stream>>>(hb, w2t, b2, out, p0);
  }
}

// Round 4
// 624.594 us; speedup vs baseline: 1.5720x; 1.0239x over previous
//
#include <hip/hip_runtime.h>
#include <stdint.h>

// Experts MLP: out[b,e] = gelu(x[b,e] @ w1[e] + b1[e]) @ w2[e] + b2[e]
// B=4 E=8 N=1024 D=1024 H=4096.
// Round 4: same 256x256 8-phase bf16 MFMA GEMM (verified r2/r3, absmax
// bit-stable). Codegen-only change: K-loop unrolled x2 so the LDS buffer
// select is compile-time (addresses hoisted), 8 running per-thread global
// pointers with immediate prefetch offsets, branch-free main loop + tail.

typedef __attribute__((ext_vector_type(8))) short short8;
typedef __attribute__((ext_vector_type(4))) float f32x4;

__device__ __forceinline__ unsigned short f2b(float f){
  union { float f; unsigned int u; } v; v.f = f;
  unsigned int r = v.u + 0x7fffu + ((v.u >> 16) & 1u);   // RNE
  return (unsigned short)(r >> 16);
}

// tanh-form GELU via exp2/rcp (verified r3)
__device__ __forceinline__ float gelu_fast(float v){
  float v2 = v * v;
  float w = v * (-2.302217529693f + -0.102943795894f * v2);
  float e = __builtin_amdgcn_exp2f(w);
  return v * __builtin_amdgcn_rcpf(1.0f + e);
}

__device__ __forceinline__ void glds16(const void* g, const void* l){
  __builtin_amdgcn_global_load_lds((const __attribute__((address_space(1))) uint32_t*)g,
                                   (__attribute__((address_space(3))) uint32_t*)l, 16, 0, 0);
}

#define BAR() do{ asm volatile("" ::: "memory"); __builtin_amdgcn_s_barrier(); asm volatile("" ::: "memory"); }while(0)

// ---------------- prep kernels (verified r1-r3) ----------------

__global__ void cvt_x_kernel(const float* __restrict__ src, unsigned short* __restrict__ dst, int n4){
  int i = blockIdx.x * blockDim.x + threadIdx.x;
  int stride = gridDim.x * blockDim.x;
  for (; i < n4; i += stride){
    float4 v = ((const float4*)src)[i];
    ushort4 o;
    o.x = f2b(v.x); o.y = f2b(v.y); o.z = f2b(v.z); o.w = f2b(v.w);
    ((ushort4*)dst)[i] = o;
  }
}

__global__ void transpose_cvt(const float* __restrict__ src, unsigned short* __restrict__ dst, int R, int C){
  __shared__ float t[64][65];
  const int e = blockIdx.z;
  src += (size_t)e * R * C;
  dst += (size_t)e * R * C;
  const int r0 = blockIdx.y * 64, c0 = blockIdx.x * 64;
  const int tid = threadIdx.x;
  const int lr = tid >> 4;
  const int lc4 = (tid & 15) * 4;
  #pragma unroll
  for (int p2 = 0; p2 < 4; p2++){
    int r = lr + p2 * 16;
    float4 v = *(const float4*)(src + (size_t)(r0 + r) * C + (c0 + lc4));
    t[r][lc4+0] = v.x; t[r][lc4+1] = v.y; t[r][lc4+2] = v.z; t[r][lc4+3] = v.w;
  }
  __syncthreads();
  #pragma unroll
  for (int p2 = 0; p2 < 4; p2++){
    int c = lr + p2 * 16;
    ushort4 o;
    o.x = f2b(t[lc4+0][c]); o.y = f2b(t[lc4+1][c]);
    o.z = f2b(t[lc4+2][c]); o.w = f2b(t[lc4+3][c]);
    *(ushort4*)(dst + (size_t)(c0 + c) * R + (r0 + lc4)) = o;
  }
}

// ---------------- 256x256 8-phase GEMM, K-unrolled x2 ----------------
// LDS rows = 64 bf16 (8 x 16B chunks); chunk c of row r at LDS chunk
// (c ^ (r&7)); LDS linear + pre-swizzled global source (rule #21).
// LDS map (shorts): A buf0 @0, A buf1 @16384, B buf0 @32768, B buf1 @49152.

template<int PHASE1>
__global__ __launch_bounds__(512, 2) void gemm256(
    const unsigned short* __restrict__ A,
    const unsigned short* __restrict__ Bt,
    const float* __restrict__ bias,
    void* __restrict__ Out,
    int p0)
{
  constexpr int M  = 1024;
  constexpr int K  = PHASE1 ? 1024 : 4096;
  constexpr int Nd = PHASE1 ? 4096 : 1024;
  constexpr int TM = M / 256, TN = Nd / 256;
  constexpr int NT = K / 64;                 // 16 or 64 (even, >=4)

  const int cpx = gridDim.x >> 3;
  const int bid = (blockIdx.x & 7) * cpx + (blockIdx.x >> 3);
  const int tn = bid % TN;
  const int t2 = bid / TN;
  const int tm = t2 % TM;
  const int cp = t2 / TM;
  const int p  = p0 + cp, e = p & 7;
  const int m0 = tm * 256, n0 = tn * 256;

  const unsigned short* Ag = A  + (size_t)(PHASE1 ? p : cp) * M * K + (size_t)m0 * K;
  const unsigned short* Bg = Bt + (size_t)e * Nd * K + (size_t)n0 * K;
  const float*          bp = bias + (size_t)e * Nd;

  __shared__ __align__(16) unsigned short lds[65536];

  const int tid = threadIdx.x;
  const int w = tid >> 6, lane = tid & 63;
  const int wr = w >> 2, wc = w & 3;          // 2 x 4 waves; wave tile 128 x 64
  const int c15 = lane & 15, q = lane >> 4;

  // staging: per-thread row within a 64-row block + swizzled chunk (shorts)
  const int trow = (w << 3) + (lane >> 3);                 // 0..63
  const int scol = ((lane & 7) ^ (trow & 7)) << 3;
  const unsigned short* pA0 = Ag + (size_t)(trow       ) * K + scol;
  const unsigned short* pA1 = Ag + (size_t)(trow +  64) * K + scol;
  const unsigned short* pA2 = Ag + (size_t)(trow + 128) * K + scol;
  const unsigned short* pA3 = Ag + (size_t)(trow + 192) * K + scol;
  const unsigned short* pB0 = Bg + (size_t)(trow       ) * K + scol;
  const unsigned short* pB1 = Bg + (size_t)(trow +  64) * K + scol;
  const unsigned short* pB2 = Bg + (size_t)(trow + 128) * K + scol;
  const unsigned short* pB3 = Bg + (size_t)(trow + 192) * K + scol;
  const int wof = w << 9;                                  // LDS dest base (shorts)

  // frag-read per-thread constants (shorts)
  const int rA64 = (wr * 128 + c15) << 6;
  const int rB64 = (wc * 64  + c15) << 6;
  const int cx0 = ( q      ^ (c15 & 7)) << 3;              // kk=0 chunk
  const int cx1 = ((q ^ 4) ^ (c15 & 7)) << 3;              // kk=1 chunk

  // bias folded into accumulator init
  float bv[4];
  #pragma unroll
  for (int nf = 0; nf < 4; ++nf) bv[nf] = bp[n0 + wc * 64 + nf * 16 + c15];

  f32x4 acc[8][4];
  #pragma unroll
  for (int i = 0; i < 8; i++)
    #pragma unroll
    for (int j = 0; j < 4; j++) acc[i][j] = (f32x4)(bv[j]);

  // ---- prologue: tile 0 into buf0 (A+B), tile 1 A rows 0..127 into buf1 ----
  glds16(pA0, lds + wof);
  glds16(pA1, lds + wof + 4096);
  glds16(pA2, lds + wof + 8192);
  glds16(pA3, lds + wof + 12288);
  glds16(pB0, lds + wof + 32768);
  glds16(pB1, lds + wof + 32768 + 4096);
  glds16(pB2, lds + wof + 32768 + 8192);
  glds16(pB3, lds + wof + 32768 + 12288);
  glds16(pA0 + 64, lds + wof + 16384);
  glds16(pA1 + 64, lds + wof + 16384 + 4096);
  asm volatile("s_waitcnt vmcnt(2)" ::: "memory");
  BAR();

  short8 af[4][2], bf0[2][2], bf1[2][2];

  // one K-tile body; CB compile-time. O1 = elem offset to tile kt+1 from the
  // running pointers (which track tile kt2), O2 = to tile kt+2.
#define TILE_BODY(CB, PF1, PF2, VM) do{                                         \
    constexpr int AB  = (CB) * 16384;                                           \
    constexpr int BB  = 32768 + (CB) * 16384;                                   \
    constexpr int ABn = ((CB) ^ 1) * 16384;                                     \
    constexpr int BBn = 32768 + (((CB) ^ 1) * 16384);                           \
    constexpr int O1  = (CB) ? 128 : 64;                                        \
    constexpr int O2  = (CB) ? 192 : 128;                                       \
    /* phase 0: quadrant (m0,n0); stage A(kt+1) rows 128..255 -> other buf */   \
    _Pragma("unroll")                                                           \
    for (int mf = 0; mf < 4; ++mf){                                             \
      af[mf][0] = *(const short8*)(lds + AB + rA64 + mf * 1024 + cx0);          \
      af[mf][1] = *(const short8*)(lds + AB + rA64 + mf * 1024 + cx1);          \
    }                                                                           \
    _Pragma("unroll")                                                           \
    for (int nf = 0; nf < 2; ++nf){                                             \
      bf0[nf][0] = *(const short8*)(lds + BB + rB64 + nf * 1024 + cx0);         \
      bf0[nf][1] = *(const short8*)(lds + BB + rB64 + nf * 1024 + cx1);         \
    }                                                                           \
    if (PF1){ glds16(pA2 + O1, lds + ABn + 8192 + wof);                         \
              glds16(pA3 + O1, lds + ABn + 12288 + wof); }                      \
    BAR();                                                                      \
    __builtin_amdgcn_s_setprio(1);                                              \
    _Pragma("unroll")                                                           \
    for (int mf = 0; mf < 4; ++mf)                                              \
      _Pragma("unroll")                                                         \
      for (int nf = 0; nf < 2; ++nf){                                           \
        acc[mf][nf] = __builtin_amdgcn_mfma_f32_16x16x32_bf16(af[mf][0], bf0[nf][0], acc[mf][nf], 0, 0, 0); \
        acc[mf][nf] = __builtin_amdgcn_mfma_f32_16x16x32_bf16(af[mf][1], bf0[nf][1], acc[mf][nf], 0, 0, 0); \
      }                                                                         \
    __builtin_amdgcn_s_setprio(0);                                              \
    BAR();                                                                      \
    /* phase 1: quadrant (m0,n1); stage B(kt+1) rows 0..127 */                  \
    _Pragma("unroll")                                                           \
    for (int nf = 0; nf < 2; ++nf){                                             \
      bf1[nf][0] = *(const short8*)(lds + BB + rB64 + 2048 + nf * 1024 + cx0);  \
      bf1[nf][1] = *(const short8*)(lds + BB + rB64 + 2048 + nf * 1024 + cx1);  \
    }                                                                           \
    if (PF1){ glds16(pB0 + O1, lds + BBn + wof);                                \
              glds16(pB1 + O1, lds + BBn + 4096 + wof); }                       \
    BAR();                                                                      \
    __builtin_amdgcn_s_setprio(1);                                              \
    _Pragma("unroll")                                                           \
    for (int mf = 0; mf < 4; ++mf)                                              \
      _Pragma("unroll")                                                         \
      for (int nf = 0; nf < 2; ++nf){                                           \
        acc[mf][2+nf] = __builtin_amdgcn_mfma_f32_16x16x32_bf16(af[mf][0], bf1[nf][0], acc[mf][2+nf], 0, 0, 0); \
        acc[mf][2+nf] = __builtin_amdgcn_mfma_f32_16x16x32_bf16(af[mf][1], bf1[nf][1], acc[mf][2+nf], 0, 0, 0); \
      }                                                                         \
    __builtin_amdgcn_s_setprio(0);                                              \
    BAR();                                                                      \
    /* phase 2: quadrant (m1,n1); stage B(kt+1) rows 128..255 */                \
    _Pragma("unroll")                                                           \
    for (int mf = 0; mf < 4; ++mf){                                             \
      af[mf][0] = *(const short8*)(lds + AB + rA64 + 4096 + mf * 1024 + cx0);   \
      af[mf][1] = *(const short8*)(lds + AB + rA64 + 4096 + mf * 1024 + cx1);   \
    }                                                                           \
    if (PF1){ glds16(pB2 + O1, lds + BBn + 8192 + wof);                         \
              glds16(pB3 + O1, lds + BBn + 12288 + wof); }                      \
    BAR();                                                                      \
    __builtin_amdgcn_s_setprio(1);                                              \
    _Pragma("unroll")                                                           \
    for (int mf = 0; mf < 4; ++mf)                                              \
      _Pragma("unroll")                                                         \
      for (int nf = 0; nf < 2; ++nf){                                           \
        acc[4+mf][2+nf] = __builtin_amdgcn_mfma_f32_16x16x32_bf16(af[mf][0], bf1[nf][0], acc[4+mf][2+nf], 0, 0, 0); \
        acc[4+mf][2+nf] = __builtin_amdgcn_mfma_f32_16x16x32_bf16(af[mf][1], bf1[nf][1], acc[4+mf][2+nf], 0, 0, 0); \
      }                                                                         \
    __builtin_amdgcn_s_setprio(0);                                              \
    BAR();                                                                      \
    /* phase 3: quadrant (m1,n0) reg-only; stage A(kt+2) rows 0..127 into      \
       CURRENT A buf (its reads ended in phase 2; barrier above orders) */      \
    if (PF2){ glds16(pA0 + O2, lds + AB + wof);                                 \
              glds16(pA1 + O2, lds + AB + 4096 + wof); }                        \
    BAR();                                                                      \
    __builtin_amdgcn_s_setprio(1);                                              \
    _Pragma("unroll")                                                           \
    for (int mf = 0; mf < 4; ++mf)                                              \
      _Pragma("unroll")                                                         \
      for (int nf = 0; nf < 2; ++nf){                                           \
        acc[4+mf][nf] = __builtin_amdgcn_mfma_f32_16x16x32_bf16(af[mf][0], bf0[nf][0], acc[4+mf][nf], 0, 0, 0); \
        acc[4+mf][nf] = __builtin_amdgcn_mfma_f32_16x16x32_bf16(af[mf][1], bf0[nf][1], acc[4+mf][nf], 0, 0, 0); \
      }                                                                         \
    __builtin_amdgcn_s_setprio(0);                                              \
    if ((VM) >= 0){                                                             \
      if ((VM) == 2) asm volatile("s_waitcnt vmcnt(2)" ::: "memory");           \
      else           asm volatile("s_waitcnt vmcnt(0)" ::: "memory");           \
    }                                                                           \
    BAR();                                                                      \
  }while(0)

  for (int kt2 = 0; kt2 + 2 < NT; kt2 += 2){
    TILE_BODY(0, 1, 1, 2);
    TILE_BODY(1, 1, 1, 2);
    pA0 += 128; pA1 += 128; pA2 += 128; pA3 += 128;
    pB0 += 128; pB1 += 128; pB2 += 128; pB3 += 128;
  }
  TILE_BODY(0, 1, 0, 0);    // tile NT-2: stage tile NT-1, drain
  TILE_BODY(1, 0, 0, -1);   // tile NT-1: compute only
#undef TILE_BODY

  // ---- epilogue: C/D layout col = lane&15, row = (lane>>4)*4 + r ----
  #pragma unroll
  for (int mf = 0; mf < 8; ++mf){
    const int row = m0 + wr * 128 + mf * 16 + q * 4;
    #pragma unroll
    for (int nf = 0; nf < 4; ++nf){
      const int col = n0 + wc * 64 + nf * 16 + c15;
      #pragma unroll
      for (int r = 0; r < 4; ++r){
        float v = acc[mf][nf][r];
        if constexpr (PHASE1){
          ((unsigned short*)Out)[(size_t)cp * M * Nd + (size_t)(row + r) * Nd + col] = f2b(gelu_fast(v));
        } else {
          ((float*)Out)[(size_t)p * M * Nd + (size_t)(row + r) * Nd + col] = v;
        }
      }
    }
  }
}

// ---------------- launch ----------------

extern "C" void kernel_launch(void* const* d_in, const int* in_sizes, int n_in,
                              void* d_out, int out_size, void* d_ws, size_t ws_size,
                              hipStream_t stream){
  const float* x  = (const float*)d_in[0];
  const float* w1 = (const float*)d_in[1];
  const float* b1 = (const float*)d_in[2];
  const float* w2 = (const float*)d_in[3];
  const float* b2 = (const float*)d_in[4];
  float* out = (float*)d_out;

  unsigned short* xb  = (unsigned short*)d_ws;
  unsigned short* w1t = (unsigned short*)((char*)d_ws + ((size_t)64  << 20));
  unsigned short* w2t = (unsigned short*)((char*)d_ws + ((size_t)128 << 20));
  unsigned short* hb  = (unsigned short*)((char*)d_ws + ((size_t)192 << 20));

  size_t avail = ws_size > ((size_t)192 << 20) ? ws_size - ((size_t)192 << 20) : 0;
  int ppc = (int)(avail / ((size_t)8 << 20));
  if (ppc > 32) ppc = 32;
  if (ppc < 1) return;

  cvt_x_kernel<<<2048, 256, 0, stream>>>(x, xb, 8 * 1024 * 1024);
  transpose_cvt<<<dim3(64, 16, 8), 256, 0, stream>>>(w1, w1t, 1024, 4096);
  transpose_cvt<<<dim3(16, 64, 8), 256, 0, stream>>>(w2, w2t, 4096, 1024);

  for (int p0 = 0; p0 < 32; p0 += ppc){
    int np = (32 - p0 < ppc) ? (32 - p0) : ppc;
    // GEMM1: h = gelu(xb @ w1t^T + b1)   [M=1024, K=1024, Nd=4096]
    gemm256<1><<<dim3(np * 4 * 16), 512, 0, stream>>>(xb, w1t, b1, hb, p0);
    // GEMM2: out = h @ w2t^T + b2        [M=1024, K=4096, Nd=1024]
    gemm256<0><<<dim3(np * 4 * 4),  512, 0, stream>>>(hb, w2t, b2, out, p0);
  }
}